// Round 2
// baseline (513.463 us; speedup 1.0000x reference)
//
#include <hip/hip_runtime.h>
#include <hip/hip_bf16.h>

// BiLSTM-CRF fused pipeline for MI355X (gfx950).
// R15: gemm+lstm fused into ONE kernel (grid 256): blocks 0-127 compute the
// length-compacted gx GEMM (one 128x256 tile per block, 8 waves, tiles in
// compacted-row order), blocks 128-255 run the lstm and spin on per-tile
// ready counters (release/acquire agent atomics + threadfence for cross-XCD
// visibility). Rows are SORTED by descending length in pack block 0, so the
// longest (critical-path) lstm blocks get their gx first and the gemm hides
// entirely under the lstm's latency-bound wall. Deadlock-free: producer
// blocks never wait; consumer blocks only wait on producers.

#define B_   256
#define T_   192
#define E_   300
#define KP   320   // padded K
#define V_   11626
#define H_   128
#define G4   512   // 4*H
#define NG   1024  // both directions
#define NT_  13
#define NEGV -10000.0f
#define HSTR 144   // hL row stride in ushorts (288B, 16B-aligned)

typedef __attribute__((ext_vector_type(8))) short bf16x8;
typedef __attribute__((ext_vector_type(4))) float f32x4;
typedef __attribute__((ext_vector_type(4))) unsigned short u16x4;

__device__ __forceinline__ unsigned short f2bf(float f) {
    return (unsigned short)(__float_as_uint(f) >> 16);   // truncation: ample threshold
}
__device__ __forceinline__ float bf2f(unsigned short h) {
    return __uint_as_float(((unsigned)h) << 16);
}
__device__ __forceinline__ float sigf(float x) {
    return __builtin_amdgcn_rcpf(1.0f + __expf(-x));
}
__device__ __forceinline__ float tanhfast(float x) {
    return __builtin_amdgcn_rcpf(1.0f + __expf(-2.0f * x)) * 2.0f - 1.0f;
}
__device__ __forceinline__ void barrier_lgkm() {
    // LDS-visibility barrier WITHOUT the forced vmcnt(0) drain of __syncthreads
    asm volatile("s_waitcnt lgkmcnt(0)\n\ts_barrier" ::: "memory");
}

// ------- pack W_ih + W_hh (frag order) + emb table (K-padded bf16) -----------
// block 0: descending-length rank sort -> perm[256], sorted prefix pfxs[257],
// zero the tile-ready counters cnt[384] and the output accumulator.
__global__ void pack_kernel(const float* __restrict__ Wf, const float* __restrict__ Wb,
                            const float* __restrict__ Whf, const float* __restrict__ Whb,
                            const float* __restrict__ emb,
                            const int* __restrict__ seq_len,
                            unsigned short* __restrict__ Wp, unsigned short* __restrict__ Whp,
                            unsigned short* __restrict__ Ep,
                            int* __restrict__ perm, int* __restrict__ pfxs,
                            int* __restrict__ cnt,
                            float* __restrict__ out) {
    int blk = blockIdx.x;
    int k = threadIdx.x;
    if (blk == 0) {
        __shared__ int Lsm[256];
        __shared__ int sc[257];
        if (k == 0) { out[0] = 0.0f; sc[0] = 0; }
        if (k < 256) Lsm[k] = min(max(seq_len[k], 1), T_);
        for (int i = k; i < 384; i += 320) cnt[i] = 0;
        __syncthreads();
        if (k < 256) {
            int L = Lsm[k]; int r = 0;
            for (int b = 0; b < 256; ++b) {
                int Lb = Lsm[b];
                r += (Lb > L) || (Lb == L && b < k);   // strict total order, descending
            }
            perm[r] = k;
            sc[r + 1] = L;
        }
        __syncthreads();
        #pragma unroll 1
        for (int off = 1; off < 257; off <<= 1) {
            int v = (k >= off && k < 257) ? sc[k - off] : 0;
            __syncthreads();
            if (k < 257) sc[k] += v;
            __syncthreads();
        }
        if (k < 257) pfxs[k] = sc[k];
    }
    if (blk < NG) {
        float v = 0.0f;
        if (k < E_) v = (blk < G4) ? Wf[blk * E_ + k] : Wb[(blk - G4) * E_ + k];
        Wp[blk * KP + k] = f2bf(v);
    } else if (blk < NG + 1024) {
        // W_hh -> bf16 fragment order: Whp[(((d*8+w)*4+j)*4+kc)*64 + lane]*8 + e
        int t = blk - NG;
        int d = t >> 9, g = t & 511;
        if (k < H_) {
            const float* src = d ? Whb : Whf;
            float v = src[g * H_ + k];
            int w = (g >> 4) & 7, j = g >> 7, colq = g & 15;
            int kc = k >> 5, quad = (k >> 3) & 3, e = k & 7;
            Whp[((((size_t)(d * 8 + w) * 4 + j) * 4 + kc) * 64 + quad * 16 + colq) * 8 + e] = f2bf(v);
        }
    } else {
        int r = blk - NG - 1024;             // vocab row 0..V_-1
        float v = (k < E_) ? emb[(size_t)r * E_ + k] : 0.0f;
        Ep[(size_t)r * KP + k] = f2bf(v);
    }
}

// ---------------- fused gemm producer + lstm consumer ------------------------
// grid 256 x 576 threads. Blocks 0-127: gemm role (one 128x256 tile per
// round, 8 active waves, wave 8 barriers only). Blocks 128-255: lstm role
// (4 sorted rows x dir), spinning until its rows' gx tiles are published.
__global__ __launch_bounds__(576, 2) void fused_kernel(
        const unsigned short* __restrict__ Ep, const int* __restrict__ sent,
        const unsigned short* __restrict__ Bw, const float* __restrict__ bF,
        const float* __restrict__ bB, const int* __restrict__ perm,
        const int* __restrict__ pfxs, int* __restrict__ cnt,
        unsigned short* __restrict__ gxP, const unsigned short* __restrict__ Whp,
        const int* __restrict__ seq_len, const float* __restrict__ Wfc,
        float* __restrict__ featsF, float* __restrict__ featsB) {

    __shared__ __align__(16) union SMU {
        struct {
            unsigned short As[128 * 64];
            unsigned short Bs[256 * 64];
            int pfx[257];
            int prm[256];
        } g;
        struct {
            unsigned short hL[2][16 * HSTR];
            int Ls[4]; int Ps[4]; int Rw[4]; int maxLs;
        } l;
    } sm;

    const int bid = blockIdx.x;
    const int tid = threadIdx.x;

    if (bid < 128) {
        // ======================= GEMM role =======================
        for (int i = tid; i < 257; i += 576) sm.g.pfx[i] = pfxs[i];
        for (int i = tid; i < 256; i += 576) sm.g.prm[i] = perm[i];
        __syncthreads();
        const int sumL = sm.g.pfx[256];
        const int Y  = (sumL + 127) >> 7;
        const int TT = Y * 4;
        const int nIter = (TT + 127) >> 7;
        const int lane = tid & 63;
        const int wave = tid >> 6;
        const int act = (tid < 512);
        const int wr = wave >> 2, wc = wave & 3;
        const int colL = lane & 15;

        for (int it = 0; it < nIter; ++it) {
            const int u = it * 128 + bid;
            const int valid = act && (u < TT);
            const int y = u >> 2, bx = u & 3;
            const int mBase = y * 128;
            const int d = bx >> 1, w0p = (bx & 1) * 4;
            int toks[2] = {0, 0};
            if (valid) {
                #pragma unroll
                for (int ja = 0; ja < 2; ja++) {
                    int ci = mBase + ((tid + 512 * ja) >> 3);
                    ci = min(ci, sumL - 1);
                    int lo = 0, hi = 256;
                    #pragma unroll
                    for (int itb = 0; itb < 8; itb++) {
                        int mid = (lo + hi) >> 1;
                        if (sm.g.pfx[mid] <= ci) lo = mid; else hi = mid;
                    }
                    toks[ja] = sent[sm.g.prm[lo] * T_ + (ci - sm.g.pfx[lo])];
                }
            }
            f32x4 acc[4][4] = {};
            for (int k0 = 0; k0 < KP; k0 += 64) {
                if (valid) {
                    #pragma unroll
                    for (int ja = 0; ja < 2; ja++) {
                        int c = tid + 512 * ja;          // A chunk 0..1023
                        int col = (c & 7) * 8;
                        __builtin_amdgcn_global_load_lds(
                            (const void*)(Ep + (size_t)toks[ja] * KP + k0 + col),
                            (void*)((char*)sm.g.As + c * 16), 16, 0, 0);
                    }
                    #pragma unroll
                    for (int jb = 0; jb < 4; jb++) {
                        int c = tid + 512 * jb;          // B chunk 0..2047
                        int col = (c & 7) * 8;
                        int row = c >> 3;                // 0..255
                        int ws = row >> 6, jj = (row >> 4) & 3, cc = row & 15;
                        int srcrow = d * 512 + (8 * jj + w0p + ws) * 16 + cc;
                        __builtin_amdgcn_global_load_lds(
                            (const void*)(Bw + (size_t)srcrow * KP + k0 + col),
                            (void*)((char*)sm.g.Bs + c * 16), 16, 0, 0);
                    }
                }
                __syncthreads();
                if (valid) {
                    #pragma unroll
                    for (int ks = 0; ks < 2; ks++) {
                        bf16x8 af[4], bfr[4];
                        #pragma unroll
                        for (int i = 0; i < 4; i++) {
                            int arow = wr * 64 + i * 16 + colL;
                            af[i]  = *(const bf16x8*)(sm.g.As + arow * 64 + ks * 32 + (lane >> 4) * 8);
                            int brow = wc * 64 + i * 16 + colL;
                            bfr[i] = *(const bf16x8*)(sm.g.Bs + brow * 64 + ks * 32 + (lane >> 4) * 8);
                        }
                        #pragma unroll
                        for (int i = 0; i < 4; i++)
                            #pragma unroll
                            for (int n2 = 0; n2 < 4; n2++)
                                acc[i][n2] = __builtin_amdgcn_mfma_f32_16x16x32_bf16(af[i], bfr[n2], acc[i][n2], 0, 0, 0);
                    }
                }
                __syncthreads();
            }
            if (valid) {
                const float* bias_d = d ? bB : bF;
                float bj[4];
                #pragma unroll
                for (int n2 = 0; n2 < 4; n2++) bj[n2] = bias_d[(8 * n2 + w0p + wc) * 16 + colL];
                #pragma unroll
                for (int i = 0; i < 4; i++)
                    #pragma unroll
                    for (int r = 0; r < 4; r++) {
                        int row = mBase + wr * 64 + i * 16 + (lane >> 4) * 4 + r;
                        if (row < sumL) {
                            u16x4 v;
                            #pragma unroll
                            for (int n2 = 0; n2 < 4; n2++) v[n2] = f2bf(acc[i][n2][r] + bj[n2]);
                            *(u16x4*)(gxP + (size_t)row * NG + d * 512 + (w0p + wc) * 64 + colL * 4) = v;
                        }
                    }
            }
            __threadfence();        // push this thread's gx stores to device scope
            __syncthreads();        // all threads' fences done
            if (u < TT && tid == 0)
                __hip_atomic_fetch_add(&cnt[y], 1, __ATOMIC_RELEASE, __HIP_MEMORY_SCOPE_AGENT);
        }
    } else {
        // ======================= LSTM role =======================
        const int lidx = bid - 128;
        const int g   = lidx >> 1;
        const int dir = lidx & 1;
        float* fOut = dir ? featsB : featsF;

        if (tid == 0) {
            const int need = pfxs[4 * g + 4];
            const int Yg = (need + 127) >> 7;
            for (int y = 0; y < Yg; ++y) {
                while (__hip_atomic_load(&cnt[y], __ATOMIC_RELAXED, __HIP_MEMORY_SCOPE_AGENT) < 4)
                    __builtin_amdgcn_s_sleep(8);
            }
            // acquire: invalidate stale cached gx lines on this CU/XCD
            (void)__hip_atomic_load(&cnt[0], __ATOMIC_ACQUIRE, __HIP_MEMORY_SCOPE_AGENT);
        }
        __syncthreads();

        const int wave = tid >> 6;
        const int lane = tid & 63;
        const int col  = lane & 15;
        const int quad = lane >> 4;

        if (tid < 4) {
            int row = perm[4 * g + tid];
            sm.l.Rw[tid] = row;
            sm.l.Ls[tid] = min(max(seq_len[row], 1), T_);
            sm.l.Ps[tid] = pfxs[4 * g + tid];
        }
        __syncthreads();
        if (tid == 0) { int m = 0; for (int i = 0; i < 4; i++) m = max(m, sm.l.Ls[i]); sm.l.maxLs = m; }
        __syncthreads();
        const int maxL = sm.l.maxLs;
        const int Lq = sm.l.Ls[quad];        // this lane's row length
        const int dNG = dir ? -NG : NG;

        bf16x8 Bf[4][4];                     // W_hh fragments (waves 0-7)
        bf16x8 Wf8[4];                       // W_fc fragments (wave 8)
        const unsigned short* rb = nullptr;  // this lane's gx base (step-0 pos)
        int ofs2 = 0;                        // element offset of the step-(s+2) load
        u16x4 gx0v = {}, gx1v = {};          // parity prefetch slots
        float* fb = nullptr;                 // wave-8 feats store base
        int foff = 0;

        if (wave < 8) {
            #pragma unroll
            for (int j = 0; j < 4; j++)
                #pragma unroll
                for (int kc = 0; kc < 4; kc++)
                    Bf[j][kc] = *(const bf16x8*)(Whp +
                        ((((size_t)(dir * 8 + wave) * 4 + j) * 4 + kc) * 64 + lane) * 8);
            int p0 = dir ? (Lq - 1) : 0;
            rb = gxP + ((size_t)(sm.l.Ps[quad] + p0)) * NG + dir * 512 + wave * 64 + col * 4;
            gx0v = *(const u16x4*)(rb);
            gx1v = *(const u16x4*)(rb + ((Lq > 1) ? dNG : 0));
            ofs2 = min(2, Lq - 1) * dNG;
        } else {
            #pragma unroll
            for (int kc = 0; kc < 4; kc++)
                #pragma unroll
                for (int e = 0; e < 8; e++) {
                    float v = (col < NT_) ? Wfc[col * 256 + dir * H_ + kc * 32 + quad * 8 + e] : 0.0f;
                    Wf8[kc][e] = (short)f2bf(v);
                }
            fb = fOut + (size_t)sm.l.Rw[quad] * T_ * NT_ + col;
            foff = (dir ? (Lq - 1) : 0) * NT_;
        }
        const int fd = dir ? -NT_ : NT_;

        float cst = 0.0f;
        bf16x8 Af[4];
        #pragma unroll
        for (int kc = 0; kc < 4; kc++)
            #pragma unroll
            for (int e = 0; e < 8; e++) Af[kc][e] = 0;   // h(-1) = 0

        auto step_body = [&](int s, u16x4& gxs, int par) {
            if (wave < 8) {
                f32x4 acc[4];
                #pragma unroll
                for (int j = 0; j < 4; j++) {
                    acc[j][0] = bf2f(gxs[j]);            // gx (+bias) seed, real row
                    acc[j][1] = 0.f; acc[j][2] = 0.f; acc[j][3] = 0.f;
                }
                // prefetch gx for step s+2 into the slot just consumed
                gxs = *(const u16x4*)(rb + ofs2);
                ofs2 = (s + 3 < Lq) ? ofs2 + dNG : ofs2;
                #pragma unroll
                for (int kc = 0; kc < 4; kc++)
                    #pragma unroll
                    for (int j = 0; j < 4; j++)
                        acc[j] = __builtin_amdgcn_mfma_f32_16x16x32_bf16(Af[kc], Bf[j][kc], acc[j], 0, 0, 0);
                float cn = sigf(acc[1][0]) * cst + sigf(acc[0][0]) * tanhfast(acc[2][0]);
                cst = cn;
                float hn = sigf(acc[3][0]) * tanhfast(cn);
                sm.l.hL[par][(quad * 4) * HSTR + wave * 16 + col] = f2bf(hn);
            }
            barrier_lgkm();
            #pragma unroll
            for (int kc = 0; kc < 4; kc++)
                Af[kc] = *(const bf16x8*)(&sm.l.hL[par][col * HSTR + kc * 32 + quad * 8]);
            if (wave == 8) {
                f32x4 fc = (f32x4){0.f, 0.f, 0.f, 0.f};
                #pragma unroll
                for (int kc = 0; kc < 4; kc++)
                    fc = __builtin_amdgcn_mfma_f32_16x16x32_bf16(Af[kc], Wf8[kc], fc, 0, 0, 0);
                if (col < NT_ && s < Lq) fb[foff] = fc[0];
                foff += fd;
            }
        };

        for (int s = 0; s < maxL; s += 2) {
            step_body(s, gx0v, 0);
            if (s + 1 < maxL) step_body(s + 1, gx1v, 1);
        }
    }
}

// ---------------- CRF: one wave per batch row, fused mean --------------------
// Alpha lives in a register (lane j owns alpha_j); redistribution via 13
// __shfl broadcasts per step -- no LDS, no barriers on the recurrence path.
// Feats staged one 16-step chunk ahead via float4 bulk loads (lanes 0..51).
__global__ __launch_bounds__(64) void crf_kernel(const float* __restrict__ fF,
                                                 const float* __restrict__ fB,
                                                 const float* __restrict__ bfc,
                                                 const float* __restrict__ trans,
                                                 const int* __restrict__ tags,
                                                 const int* __restrict__ seq_len,
                                                 float* __restrict__ out) {
    __shared__ __align__(16) float feat_lds[2 * 208];
    __shared__ float Tlds[NT_ * NT_];
    const int lane = threadIdx.x;
    const int b = blockIdx.x;
    const int Lb = min(max(seq_len[b], 1), T_);
    const float* fFb = fF + (size_t)b * T_ * NT_;
    const float* fBb = fB + (size_t)b * T_ * NT_;
    const int* tg = tags + (size_t)b * T_;

    for (int i = lane; i < NT_ * NT_; i += 64) Tlds[i] = trans[i];

    const int jc = min(lane, NT_ - 1);
    float Tj[NT_];
    #pragma unroll
    for (int i = 0; i < NT_; i++) Tj[i] = trans[jc * NT_ + i];
    const float bj  = bfc[jc];
    const float T10 = trans[10 * NT_ + jc];
    float alj = (jc == 0 && lane == 0) ? 0.0f : NEGV;   // alpha_j in-register

    // stage chunk 0
    const int e0 = lane * 4;
    const bool ldact = (lane < 52);
    float4 vF = {}, vB = {};
    if (ldact) { vF = *(const float4*)(fFb + e0); vB = *(const float4*)(fBb + e0); }

    #pragma unroll 1
    for (int c = 0; c < 12; ++c) {
        if (ldact) {
            float4 w;
            #pragma unroll
            for (int k = 0; k < 4; k++) {
                unsigned g = (unsigned)(c * 208 + e0 + k);
                unsigned t = g / 13u;
                float s = ((const float*)&vF)[k] + ((const float*)&vB)[k];
                ((float*)&w)[k] = (t < (unsigned)Lb) ? s : 0.0f;
            }
            *(float4*)&feat_lds[(c & 1) * 208 + e0] = w;
            if (c < 11) {
                vF = *(const float4*)(fFb + (c + 1) * 208 + e0);
                vB = *(const float4*)(fBb + (c + 1) * 208 + e0);
            }
        }
        barrier_lgkm();   // WAR on the other buffer protected one chunk later
        const int fbase = (c & 1) * 208;
        for (int tt = 0; tt < 16; ++tt) {
            float a0  = __shfl(alj, 0, 64),  a1  = __shfl(alj, 1, 64);
            float a2  = __shfl(alj, 2, 64),  a3  = __shfl(alj, 3, 64);
            float a4  = __shfl(alj, 4, 64),  a5  = __shfl(alj, 5, 64);
            float a6  = __shfl(alj, 6, 64),  a7  = __shfl(alj, 7, 64);
            float a8  = __shfl(alj, 8, 64),  a9  = __shfl(alj, 9, 64);
            float a10 = __shfl(alj, 10, 64), a11 = __shfl(alj, 11, 64);
            float a12 = __shfl(alj, 12, 64);
            float feat = feat_lds[fbase + tt * NT_ + jc];
            float v0 = a0 + Tj[0],  v1 = a1 + Tj[1],  v2 = a2 + Tj[2],  v3 = a3 + Tj[3];
            float v4 = a4 + Tj[4],  v5 = a5 + Tj[5],  v6 = a6 + Tj[6],  v7 = a7 + Tj[7];
            float v8 = a8 + Tj[8],  v9 = a9 + Tj[9],  v10 = a10 + Tj[10], v11 = a11 + Tj[11];
            float v12 = a12 + Tj[12];
            float p0 = fmaxf(v0, v1), p1 = fmaxf(v2, v3), p2 = fmaxf(v4, v5);
            float p3 = fmaxf(v6, v7), p4 = fmaxf(v8, v9), p5 = fmaxf(v10, v11);
            float q0 = fmaxf(p0, p1), q1 = fmaxf(p2, p3), q2 = fmaxf(p4, p5);
            float m = fmaxf(fmaxf(q0, q1), fmaxf(q2, v12));
            float e0_ = __expf(v0 - m),  e1_ = __expf(v1 - m),  e2_ = __expf(v2 - m);
            float e3_ = __expf(v3 - m),  e4_ = __expf(v4 - m),  e5_ = __expf(v5 - m);
            float e6_ = __expf(v6 - m),  e7_ = __expf(v7 - m),  e8_ = __expf(v8 - m);
            float e9_ = __expf(v9 - m),  e10_ = __expf(v10 - m), e11_ = __expf(v11 - m);
            float e12_ = __expf(v12 - m);
            float s0 = e0_ + e1_, s1 = e2_ + e3_, s2 = e4_ + e5_, s3 = e6_ + e7_;
            float s4 = e8_ + e9_, s5 = e10_ + e11_;
            float u0 = s0 + s1, u1 = s2 + s3, u2 = s4 + s5;
            float ss = (u0 + u1) + (u2 + e12_);
            alj = m + __logf(ss) + feat + bj;
        }
    }

    // gold score: t = lane, lane+64, lane+128
    float gp = 0.0f;
    #pragma unroll
    for (int u = 0; u < 3; ++u) {
        int t = lane + u * 64;
        int tt_ = tg[t];
        int pv = (t == 0) ? 0 : tg[t - 1];
        float e = bfc[tt_];
        if (t < Lb) e += fFb[t * NT_ + tt_] + fBb[t * NT_ + tt_];
        gp += Tlds[tt_ * NT_ + pv] + e;
    }
    #pragma unroll
    for (int o = 32; o > 0; o >>= 1) gp += __shfl_down(gp, o, 64);

    // fwd = LSE_j(alphaT[j] + trans[10][j])
    float vj = (lane < NT_) ? (alj + T10) : -3.0e38f;
    float mm = vj;
    #pragma unroll
    for (int o = 32; o > 0; o >>= 1) mm = fmaxf(mm, __shfl_down(mm, o, 64));
    mm = __shfl(mm, 0, 64);
    float se = (lane < NT_) ? __expf(vj - mm) : 0.0f;
    #pragma unroll
    for (int o = 32; o > 0; o >>= 1) se += __shfl_down(se, o, 64);
    if (lane == 0) {
        float fwd = mm + __logf(se);
        float gold = gp + Tlds[10 * NT_ + tg[T_ - 1]];
        atomicAdd(out, (fwd - gold) * (1.0f / 256.0f));
    }
}

extern "C" void kernel_launch(void* const* d_in, const int* in_sizes, int n_in,
                              void* d_out, int out_size, void* d_ws, size_t ws_size,
                              hipStream_t stream) {
    const int*   sentence  = (const int*)d_in[0];
    const int*   seq_len   = (const int*)d_in[1];
    const int*   tags      = (const int*)d_in[2];
    const float* embedding = (const float*)d_in[3];
    const float* W_ih_f    = (const float*)d_in[4];
    const float* W_hh_f    = (const float*)d_in[5];
    const float* b_f       = (const float*)d_in[6];
    const float* W_ih_b    = (const float*)d_in[7];
    const float* W_hh_b    = (const float*)d_in[8];
    const float* b_b       = (const float*)d_in[9];
    const float* W_fc      = (const float*)d_in[10];
    const float* b_fc      = (const float*)d_in[11];
    const float* trans     = (const float*)d_in[12];
    float* out = (float*)d_out;

    char* ws = (char*)d_ws;
    unsigned short* Wp  = (unsigned short*)(ws);                         // 655,360
    unsigned short* Ep  = (unsigned short*)(ws + 655360);                // 11626*320*2 = 7,440,640
    unsigned short* gx  = (unsigned short*)(ws + 8096000);               // 100,663,296
    float* featsF = (float*)(ws + 108759296);                            // 2,555,904
    float* featsB = (float*)(ws + 111315200);                            // 2,555,904
    unsigned short* Whp = (unsigned short*)(ws + 113871104);             // 262,144
    int* perm = (int*)(ws + 114133248);                                  // 1,024
    int* pfxs = (int*)(ws + 114134272);                                  // 1,028 (pad to 1,040)
    int* cnt  = (int*)(ws + 114135312);                                  // 384*4 = 1,536

    pack_kernel<<<NG + 1024 + V_, KP, 0, stream>>>(W_ih_f, W_ih_b, W_hh_f, W_hh_b,
                                                   embedding, seq_len, Wp, Whp, Ep,
                                                   perm, pfxs, cnt, out);
    fused_kernel<<<256, 576, 0, stream>>>(Ep, sentence, Wp, b_f, b_b,
                                          perm, pfxs, cnt, gx, Whp, seq_len,
                                          W_fc, featsF, featsB);
    crf_kernel<<<B_, 64, 0, stream>>>(featsF, featsB, b_fc, trans, tags, seq_len, out);
}

// Round 3
// 285.795 us; speedup vs baseline: 1.7966x; 1.7966x over previous
//
#include <hip/hip_runtime.h>
#include <hip/hip_bf16.h>

// BiLSTM-CRF fused pipeline for MI355X (gfx950).
// R16: R14 base (length-compacted gx GEMM; proven 289.8us) + XCD-swizzled
// gemm grid: all 8 bx-blocks of one y-tile (which share the same gathered
// A panel) are mapped to the SAME XCD (id%8 = XCD, consecutive slots), so
// the 80KB A panel is fetched once per XCD L2 instead of 8x through IF.
// Pure grid-index bijection -- zero semantic change vs R14. R15's
// producer-consumer fusion reverted: gemm at 1 block/CU had no wave overlap
// (every barrier exposed full HBM latency) and short-seq lstm blocks waited
// on the global prefix -> wall ~ slow_gemm + tail (362us measured).

#define B_   256
#define T_   192
#define E_   300
#define KP   320   // padded K
#define V_   11626
#define H_   128
#define G4   512   // 4*H
#define NG   1024  // both directions
#define NT_  13
#define NEGV -10000.0f
#define HSTR 144   // hL row stride in ushorts (288B, 16B-aligned)

typedef __attribute__((ext_vector_type(8))) short bf16x8;
typedef __attribute__((ext_vector_type(4))) float f32x4;
typedef __attribute__((ext_vector_type(4))) unsigned short u16x4;

__device__ __forceinline__ unsigned short f2bf(float f) {
    return (unsigned short)(__float_as_uint(f) >> 16);   // truncation: ample threshold
}
__device__ __forceinline__ float bf2f(unsigned short h) {
    return __uint_as_float(((unsigned)h) << 16);
}
__device__ __forceinline__ float sigf(float x) {
    return __builtin_amdgcn_rcpf(1.0f + __expf(-x));
}
__device__ __forceinline__ float tanhfast(float x) {
    return __builtin_amdgcn_rcpf(1.0f + __expf(-2.0f * x)) * 2.0f - 1.0f;
}
__device__ __forceinline__ void barrier_lgkm() {
    // LDS-visibility barrier WITHOUT the forced vmcnt(0) drain of __syncthreads
    asm volatile("s_waitcnt lgkmcnt(0)\n\ts_barrier" ::: "memory");
}

// ------- pack W_ih + W_hh (frag order) + emb table (K-padded bf16) -----------
// block 0 additionally builds prefix[0..256]: prefix[b] = sum of clamped
// lengths of rows < b (prefix[256] = sumL).
__global__ void pack_kernel(const float* __restrict__ Wf, const float* __restrict__ Wb,
                            const float* __restrict__ Whf, const float* __restrict__ Whb,
                            const float* __restrict__ emb,
                            const int* __restrict__ seq_len,
                            unsigned short* __restrict__ Wp, unsigned short* __restrict__ Whp,
                            unsigned short* __restrict__ Ep, int* __restrict__ prefix,
                            float* __restrict__ out) {
    int blk = blockIdx.x;
    int k = threadIdx.x;
    if (blk == 0) {
        __shared__ int sc[257];
        if (k == 0) { sc[0] = 0; out[0] = 0.0f; }   // zero accumulator for crf atomicAdd
        if (k < 256) sc[k + 1] = min(max(seq_len[k], 1), T_);
        __syncthreads();
        #pragma unroll 1
        for (int off = 1; off < 257; off <<= 1) {
            int v = (k >= off && k < 257) ? sc[k - off] : 0;
            __syncthreads();
            if (k < 257) sc[k] += v;
            __syncthreads();
        }
        if (k < 257) prefix[k] = sc[k];
    }
    if (blk < NG) {
        float v = 0.0f;
        if (k < E_) v = (blk < G4) ? Wf[blk * E_ + k] : Wb[(blk - G4) * E_ + k];
        Wp[blk * KP + k] = f2bf(v);
    } else if (blk < NG + 1024) {
        // W_hh -> bf16 fragment order: Whp[(((d*8+w)*4+j)*4+kc)*64 + lane]*8 + e
        int t = blk - NG;
        int d = t >> 9, g = t & 511;
        if (k < H_) {
            const float* src = d ? Whb : Whf;
            float v = src[g * H_ + k];
            int w = (g >> 4) & 7, j = g >> 7, colq = g & 15;
            int kc = k >> 5, quad = (k >> 3) & 3, e = k & 7;
            Whp[((((size_t)(d * 8 + w) * 4 + j) * 4 + kc) * 64 + quad * 16 + colq) * 8 + e] = f2bf(v);
        }
    } else {
        int r = blk - NG - 1024;             // vocab row 0..V_-1
        float v = (k < E_) ? emb[(size_t)r * E_ + k] : 0.0f;
        Ep[(size_t)r * KP + k] = f2bf(v);
    }
}

// ---------------- bf16 MFMA GEMM: gx = emb[sent] @ W^T + bias, permuted ------
// M-dimension is length-compacted: row ci in [0,sumL) maps to (b,t) via the
// prefix array (binary search in LDS). Blocks beyond sumL exit immediately.
// Grid is a 1-D bijection of (y,bx) chosen so the 8 bx-blocks of one y-tile
// (same A panel) land on the SAME XCD: id = slot*8 + xcd, y = 8*(slot>>3) +
// xcd, bx = slot&7 -> for fixed y, xcd = y&7 and bx spans consecutive slots.
__global__ __launch_bounds__(256, 3) void gemm_kernel(const unsigned short* __restrict__ Ep,
                                                      const int* __restrict__ sent,
                                                      const unsigned short* __restrict__ Bw,
                                                      const float* __restrict__ bF,
                                                      const float* __restrict__ bB,
                                                      const int* __restrict__ prefix,
                                                      unsigned short* __restrict__ C) {
    __shared__ __align__(16) unsigned short As[128 * 64];
    __shared__ __align__(16) unsigned short Bs[128 * 64];
    __shared__ int pfx[257];
    const int tid  = threadIdx.x;
    for (int i = tid; i < 257; i += 256) pfx[i] = prefix[i];
    __syncthreads();
    const int sumL = pfx[256];
    const int bid  = blockIdx.x;
    const int xcd  = bid & 7;
    const int slot = bid >> 3;
    const int y    = ((slot >> 3) << 3) + xcd;   // 8*(slot/8) + xcd
    const int bx   = slot & 7;
    const int mBase = y * 128;
    if (mBase >= sumL) return;
    const int lane = tid & 63;
    const int wave = tid >> 6;
    const int wr = wave >> 1, wc = wave & 1;
    const int colL = lane & 15;
    const int d  = bx >> 2;
    const int w0 = (bx & 3) * 2;
    int toks[4];
    #pragma unroll
    for (int j = 0; j < 4; j++) {
        int ci = mBase + ((tid + 256 * j) >> 3);
        ci = min(ci, sumL - 1);
        int lo = 0, hi = 256;            // largest b with pfx[b] <= ci  (8 steps)
        #pragma unroll
        for (int it = 0; it < 8; it++) {
            int mid = (lo + hi) >> 1;
            if (pfx[mid] <= ci) lo = mid; else hi = mid;
        }
        toks[j] = sent[lo * T_ + (ci - pfx[lo])];
    }
    f32x4 acc[4][4] = {};
    for (int k0 = 0; k0 < KP; k0 += 64) {
        #pragma unroll
        for (int j = 0; j < 4; j++) {
            int c   = tid + 256 * j;       // 16B chunk id 0..1023; LDS offset = c*16
            int col = (c & 7) * 8;
            __builtin_amdgcn_global_load_lds(
                (const void*)(Ep + (size_t)toks[j] * KP + k0 + col),
                (void*)((char*)As + c * 16), 16, 0, 0);
            int row = c >> 3;
            int ws = row >> 6, jj = (row >> 4) & 3, cc = row & 15;
            int srcrow = d * 512 + (8 * jj + w0 + ws) * 16 + cc;
            __builtin_amdgcn_global_load_lds(
                (const void*)(Bw + (size_t)srcrow * KP + k0 + col),
                (void*)((char*)Bs + c * 16), 16, 0, 0);
        }
        __syncthreads();
        #pragma unroll
        for (int ks = 0; ks < 2; ks++) {
            bf16x8 af[4], bfr[4];
            #pragma unroll
            for (int i = 0; i < 4; i++) {
                int arow = wr * 64 + i * 16 + colL;
                af[i]  = *(const bf16x8*)(As + arow * 64 + ks * 32 + (lane >> 4) * 8);
                int brow = wc * 64 + i * 16 + colL;
                bfr[i] = *(const bf16x8*)(Bs + brow * 64 + ks * 32 + (lane >> 4) * 8);
            }
            #pragma unroll
            for (int i = 0; i < 4; i++)
                #pragma unroll
                for (int n2 = 0; n2 < 4; n2++)
                    acc[i][n2] = __builtin_amdgcn_mfma_f32_16x16x32_bf16(af[i], bfr[n2], acc[i][n2], 0, 0, 0);
        }
        __syncthreads();
    }
    const float* bias_d = d ? bB : bF;
    float bj[4];
    #pragma unroll
    for (int n2 = 0; n2 < 4; n2++) bj[n2] = bias_d[(8 * n2 + w0 + wc) * 16 + colL];
    #pragma unroll
    for (int i = 0; i < 4; i++)
        #pragma unroll
        for (int r = 0; r < 4; r++) {
            int row = mBase + wr * 64 + i * 16 + (lane >> 4) * 4 + r;
            if (row < sumL) {
                u16x4 v;
                #pragma unroll
                for (int n2 = 0; n2 < 4; n2++) v[n2] = f2bf(acc[i][n2][r] + bj[n2]);
                *(u16x4*)(C + (size_t)row * NG + d * 512 + (w0 + wc) * 64 + colL * 4) = v;
            }
        }
}

// ---------------- MFMA LSTM recurrence + feats projection --------------------
// grid 128: block = (4 batch rows, dir). 576 threads = 9 waves (R7 structure).
// gx is length-compacted: step t of row lives at (prefix[row]+t)*NG.
__global__ __launch_bounds__(576, 1) void lstm_kernel(const unsigned short* __restrict__ gxP,
                                                      const unsigned short* __restrict__ Whp,
                                                      const int* __restrict__ seq_len,
                                                      const int* __restrict__ prefix,
                                                      const float* __restrict__ Wfc,
                                                      float* __restrict__ featsF,
                                                      float* __restrict__ featsB) {
    __shared__ __align__(16) unsigned short hL[2][16 * HSTR];
    __shared__ int Ls[4];
    __shared__ int Ps[4];
    __shared__ int maxLs;
    const int tid  = threadIdx.x;
    const int wave = tid >> 6;
    const int lane = tid & 63;
    const int col  = lane & 15;
    const int quad = lane >> 4;
    const int dir  = blockIdx.x & 1;
    const int b0   = (blockIdx.x >> 1) * 4;
    float* fOut = dir ? featsB : featsF;

    if (tid < 4) {
        Ls[tid] = min(max(seq_len[b0 + tid], 1), T_);
        Ps[tid] = prefix[b0 + tid];
    }
    __syncthreads();
    if (tid == 0) { int m = 0; for (int i = 0; i < 4; i++) m = max(m, Ls[i]); maxLs = m; }
    __syncthreads();
    const int maxL = maxLs;
    const int Lq = Ls[quad];              // this lane's row length
    const int dNG = dir ? -NG : NG;

    bf16x8 Bf[4][4];                      // W_hh fragments (waves 0-7)
    bf16x8 Wf8[4];                        // W_fc fragments (wave 8)
    const unsigned short* rb = nullptr;   // this lane's gx base (step-0 pos)
    int ofs2 = 0;                         // element offset of the step-(s+2) load
    u16x4 gx0v = {}, gx1v = {};           // parity prefetch slots
    float* fb = nullptr;                  // wave-8 feats store base
    int foff = 0;

    if (wave < 8) {
        #pragma unroll
        for (int j = 0; j < 4; j++)
            #pragma unroll
            for (int kc = 0; kc < 4; kc++)
                Bf[j][kc] = *(const bf16x8*)(Whp +
                    ((((size_t)(dir * 8 + wave) * 4 + j) * 4 + kc) * 64 + lane) * 8);
        int p0 = dir ? (Lq - 1) : 0;
        rb = gxP + ((size_t)(Ps[quad] + p0)) * NG + dir * 512 + wave * 64 + col * 4;
        gx0v = *(const u16x4*)(rb);
        gx1v = *(const u16x4*)(rb + ((Lq > 1) ? dNG : 0));
        ofs2 = min(2, Lq - 1) * dNG;
    } else {
        #pragma unroll
        for (int kc = 0; kc < 4; kc++)
            #pragma unroll
            for (int e = 0; e < 8; e++) {
                float v = (col < NT_) ? Wfc[col * 256 + dir * H_ + kc * 32 + quad * 8 + e] : 0.0f;
                Wf8[kc][e] = (short)f2bf(v);
            }
        fb = fOut + (size_t)(b0 + quad) * T_ * NT_ + col;
        foff = (dir ? (Lq - 1) : 0) * NT_;
    }
    const int fd = dir ? -NT_ : NT_;

    float cst = 0.0f;
    bf16x8 Af[4];
    #pragma unroll
    for (int kc = 0; kc < 4; kc++)
        #pragma unroll
        for (int e = 0; e < 8; e++) Af[kc][e] = 0;   // h(-1) = 0

    auto step_body = [&](int s, u16x4& gxs, int par) {
        if (wave < 8) {
            f32x4 acc[4];
            #pragma unroll
            for (int j = 0; j < 4; j++) {
                acc[j][0] = bf2f(gxs[j]);            // gx (+bias) seed, real row
                acc[j][1] = 0.f; acc[j][2] = 0.f; acc[j][3] = 0.f;
            }
            // prefetch gx for step s+2 into the slot just consumed
            gxs = *(const u16x4*)(rb + ofs2);
            ofs2 = (s + 3 < Lq) ? ofs2 + dNG : ofs2;
            #pragma unroll
            for (int kc = 0; kc < 4; kc++)
                #pragma unroll
                for (int j = 0; j < 4; j++)
                    acc[j] = __builtin_amdgcn_mfma_f32_16x16x32_bf16(Af[kc], Bf[j][kc], acc[j], 0, 0, 0);
            float cn = sigf(acc[1][0]) * cst + sigf(acc[0][0]) * tanhfast(acc[2][0]);
            cst = cn;
            float hn = sigf(acc[3][0]) * tanhfast(cn);
            hL[par][(quad * 4) * HSTR + wave * 16 + col] = f2bf(hn);
        }
        barrier_lgkm();
        #pragma unroll
        for (int kc = 0; kc < 4; kc++)
            Af[kc] = *(const bf16x8*)(&hL[par][col * HSTR + kc * 32 + quad * 8]);
        if (wave == 8) {
            f32x4 fc = (f32x4){0.f, 0.f, 0.f, 0.f};
            #pragma unroll
            for (int kc = 0; kc < 4; kc++)
                fc = __builtin_amdgcn_mfma_f32_16x16x32_bf16(Af[kc], Wf8[kc], fc, 0, 0, 0);
            if (col < NT_ && s < Lq) fb[foff] = fc[0];
            foff += fd;
        }
    };

    for (int s = 0; s < maxL; s += 2) {
        step_body(s, gx0v, 0);
        if (s + 1 < maxL) step_body(s + 1, gx1v, 1);
    }
}

// ---------------- CRF: one wave per batch row, fused mean --------------------
// Alpha lives in a register (lane j owns alpha_j); redistribution via 13
// __shfl broadcasts per step -- no LDS, no barriers on the recurrence path.
// Feats staged one 16-step chunk ahead via float4 bulk loads (lanes 0..51).
__global__ __launch_bounds__(64) void crf_kernel(const float* __restrict__ fF,
                                                 const float* __restrict__ fB,
                                                 const float* __restrict__ bfc,
                                                 const float* __restrict__ trans,
                                                 const int* __restrict__ tags,
                                                 const int* __restrict__ seq_len,
                                                 float* __restrict__ out) {
    __shared__ __align__(16) float feat_lds[2 * 208];
    __shared__ float Tlds[NT_ * NT_];
    const int lane = threadIdx.x;
    const int b = blockIdx.x;
    const int Lb = min(max(seq_len[b], 1), T_);
    const float* fFb = fF + (size_t)b * T_ * NT_;
    const float* fBb = fB + (size_t)b * T_ * NT_;
    const int* tg = tags + (size_t)b * T_;

    for (int i = lane; i < NT_ * NT_; i += 64) Tlds[i] = trans[i];

    const int jc = min(lane, NT_ - 1);
    float Tj[NT_];
    #pragma unroll
    for (int i = 0; i < NT_; i++) Tj[i] = trans[jc * NT_ + i];
    const float bj  = bfc[jc];
    const float T10 = trans[10 * NT_ + jc];
    float alj = (jc == 0 && lane == 0) ? 0.0f : NEGV;   // alpha_j in-register

    // stage chunk 0
    const int e0 = lane * 4;
    const bool ldact = (lane < 52);
    float4 vF = {}, vB = {};
    if (ldact) { vF = *(const float4*)(fFb + e0); vB = *(const float4*)(fBb + e0); }

    #pragma unroll 1
    for (int c = 0; c < 12; ++c) {
        if (ldact) {
            float4 w;
            #pragma unroll
            for (int k = 0; k < 4; k++) {
                unsigned g = (unsigned)(c * 208 + e0 + k);
                unsigned t = g / 13u;
                float s = ((const float*)&vF)[k] + ((const float*)&vB)[k];
                ((float*)&w)[k] = (t < (unsigned)Lb) ? s : 0.0f;
            }
            *(float4*)&feat_lds[(c & 1) * 208 + e0] = w;
            if (c < 11) {
                vF = *(const float4*)(fFb + (c + 1) * 208 + e0);
                vB = *(const float4*)(fBb + (c + 1) * 208 + e0);
            }
        }
        barrier_lgkm();   // WAR on the other buffer protected one chunk later
        const int fbase = (c & 1) * 208;
        for (int tt = 0; tt < 16; ++tt) {
            float a0  = __shfl(alj, 0, 64),  a1  = __shfl(alj, 1, 64);
            float a2  = __shfl(alj, 2, 64),  a3  = __shfl(alj, 3, 64);
            float a4  = __shfl(alj, 4, 64),  a5  = __shfl(alj, 5, 64);
            float a6  = __shfl(alj, 6, 64),  a7  = __shfl(alj, 7, 64);
            float a8  = __shfl(alj, 8, 64),  a9  = __shfl(alj, 9, 64);
            float a10 = __shfl(alj, 10, 64), a11 = __shfl(alj, 11, 64);
            float a12 = __shfl(alj, 12, 64);
            float feat = feat_lds[fbase + tt * NT_ + jc];
            float v0 = a0 + Tj[0],  v1 = a1 + Tj[1],  v2 = a2 + Tj[2],  v3 = a3 + Tj[3];
            float v4 = a4 + Tj[4],  v5 = a5 + Tj[5],  v6 = a6 + Tj[6],  v7 = a7 + Tj[7];
            float v8 = a8 + Tj[8],  v9 = a9 + Tj[9],  v10 = a10 + Tj[10], v11 = a11 + Tj[11];
            float v12 = a12 + Tj[12];
            float p0 = fmaxf(v0, v1), p1 = fmaxf(v2, v3), p2 = fmaxf(v4, v5);
            float p3 = fmaxf(v6, v7), p4 = fmaxf(v8, v9), p5 = fmaxf(v10, v11);
            float q0 = fmaxf(p0, p1), q1 = fmaxf(p2, p3), q2 = fmaxf(p4, p5);
            float m = fmaxf(fmaxf(q0, q1), fmaxf(q2, v12));
            float e0_ = __expf(v0 - m),  e1_ = __expf(v1 - m),  e2_ = __expf(v2 - m);
            float e3_ = __expf(v3 - m),  e4_ = __expf(v4 - m),  e5_ = __expf(v5 - m);
            float e6_ = __expf(v6 - m),  e7_ = __expf(v7 - m),  e8_ = __expf(v8 - m);
            float e9_ = __expf(v9 - m),  e10_ = __expf(v10 - m), e11_ = __expf(v11 - m);
            float e12_ = __expf(v12 - m);
            float s0 = e0_ + e1_, s1 = e2_ + e3_, s2 = e4_ + e5_, s3 = e6_ + e7_;
            float s4 = e8_ + e9_, s5 = e10_ + e11_;
            float u0 = s0 + s1, u1 = s2 + s3, u2 = s4 + s5;
            float ss = (u0 + u1) + (u2 + e12_);
            alj = m + __logf(ss) + feat + bj;
        }
    }

    // gold score: t = lane, lane+64, lane+128
    float gp = 0.0f;
    #pragma unroll
    for (int u = 0; u < 3; ++u) {
        int t = lane + u * 64;
        int tt_ = tg[t];
        int pv = (t == 0) ? 0 : tg[t - 1];
        float e = bfc[tt_];
        if (t < Lb) e += fFb[t * NT_ + tt_] + fBb[t * NT_ + tt_];
        gp += Tlds[tt_ * NT_ + pv] + e;
    }
    #pragma unroll
    for (int o = 32; o > 0; o >>= 1) gp += __shfl_down(gp, o, 64);

    // fwd = LSE_j(alphaT[j] + trans[10][j])
    float vj = (lane < NT_) ? (alj + T10) : -3.0e38f;
    float mm = vj;
    #pragma unroll
    for (int o = 32; o > 0; o >>= 1) mm = fmaxf(mm, __shfl_down(mm, o, 64));
    mm = __shfl(mm, 0, 64);
    float se = (lane < NT_) ? __expf(vj - mm) : 0.0f;
    #pragma unroll
    for (int o = 32; o > 0; o >>= 1) se += __shfl_down(se, o, 64);
    if (lane == 0) {
        float fwd = mm + __logf(se);
        float gold = gp + Tlds[10 * NT_ + tg[T_ - 1]];
        atomicAdd(out, (fwd - gold) * (1.0f / 256.0f));
    }
}

extern "C" void kernel_launch(void* const* d_in, const int* in_sizes, int n_in,
                              void* d_out, int out_size, void* d_ws, size_t ws_size,
                              hipStream_t stream) {
    const int*   sentence  = (const int*)d_in[0];
    const int*   seq_len   = (const int*)d_in[1];
    const int*   tags      = (const int*)d_in[2];
    const float* embedding = (const float*)d_in[3];
    const float* W_ih_f    = (const float*)d_in[4];
    const float* W_hh_f    = (const float*)d_in[5];
    const float* b_f       = (const float*)d_in[6];
    const float* W_ih_b    = (const float*)d_in[7];
    const float* W_hh_b    = (const float*)d_in[8];
    const float* b_b       = (const float*)d_in[9];
    const float* W_fc      = (const float*)d_in[10];
    const float* b_fc      = (const float*)d_in[11];
    const float* trans     = (const float*)d_in[12];
    float* out = (float*)d_out;

    char* ws = (char*)d_ws;
    const size_t M = (size_t)B_ * T_;                   // 49152
    unsigned short* Wp  = (unsigned short*)(ws);                         // 655,360
    unsigned short* Ep  = (unsigned short*)(ws + 655360);                // 11626*320*2 = 7,440,640
    unsigned short* gx  = (unsigned short*)(ws + 8096000);               // 100,663,296
    float* featsF = (float*)(ws + 108759296);                            // 2,555,904
    float* featsB = (float*)(ws + 111315200);                            // 2,555,904
    unsigned short* Whp = (unsigned short*)(ws + 113871104);             // 262,144
    int* prefix = (int*)(ws + 114133248);                                // 257*4 = 1,028

    pack_kernel<<<NG + 1024 + V_, KP, 0, stream>>>(W_ih_f, W_ih_b, W_hh_f, W_hh_b,
                                                   embedding, seq_len, Wp, Whp, Ep, prefix, out);
    gemm_kernel<<<(int)(M / 128) * 8, 256, 0, stream>>>(Ep, sentence, Wp, b_f, b_b, prefix, gx);
    lstm_kernel<<<128, 576, 0, stream>>>(gx, Whp, seq_len, prefix, W_fc, featsF, featsB);
    crf_kernel<<<B_, 64, 0, stream>>>(featsF, featsB, b_fc, trans, tags, seq_len, out);
}

// Round 4
// 279.992 us; speedup vs baseline: 1.8338x; 1.0207x over previous
//
#include <hip/hip_runtime.h>
#include <hip/hip_bf16.h>

// BiLSTM-CRF fused pipeline for MI355X (gfx950).
// R17: latency-chain cuts on both serial kernels, on the R16 base (285.8us).
//  - lstm: per-gate MFMA chain flattened from one 4-deep chain to two
//    independent 2-deep chains seeded from a persistent zero C operand
//    (gx seed added as a scalar at the end). Critical path 4L -> 2L MFMA
//    latencies per step; +16 AGPR (fits 3 waves/SIMD for the 9-wave block).
//  - crf: the 13 constant-lane __shfl broadcasts (ds_bpermute, ~30cy LDS
//    latency at the head of each of 192 chained steps) replaced with
//    __builtin_amdgcn_readlane (SGPR broadcast); max tree regrouped into
//    fmaxf triples (v_max3_f32, depth 4->3). Bit-identical crf numerics.
// gemm/pack unchanged (R16 XCD-swizzled, length-compacted).

#define B_   256
#define T_   192
#define E_   300
#define KP   320   // padded K
#define V_   11626
#define H_   128
#define G4   512   // 4*H
#define NG   1024  // both directions
#define NT_  13
#define NEGV -10000.0f
#define HSTR 144   // hL row stride in ushorts (288B, 16B-aligned)

typedef __attribute__((ext_vector_type(8))) short bf16x8;
typedef __attribute__((ext_vector_type(4))) float f32x4;
typedef __attribute__((ext_vector_type(4))) unsigned short u16x4;

__device__ __forceinline__ unsigned short f2bf(float f) {
    return (unsigned short)(__float_as_uint(f) >> 16);   // truncation: ample threshold
}
__device__ __forceinline__ float bf2f(unsigned short h) {
    return __uint_as_float(((unsigned)h) << 16);
}
__device__ __forceinline__ float sigf(float x) {
    return __builtin_amdgcn_rcpf(1.0f + __expf(-x));
}
__device__ __forceinline__ float tanhfast(float x) {
    return __builtin_amdgcn_rcpf(1.0f + __expf(-2.0f * x)) * 2.0f - 1.0f;
}
__device__ __forceinline__ float bcast(float v, int lane) {
    return __uint_as_float(__builtin_amdgcn_readlane(__float_as_uint(v), lane));
}
__device__ __forceinline__ void barrier_lgkm() {
    // LDS-visibility barrier WITHOUT the forced vmcnt(0) drain of __syncthreads
    asm volatile("s_waitcnt lgkmcnt(0)\n\ts_barrier" ::: "memory");
}

// ------- pack W_ih + W_hh (frag order) + emb table (K-padded bf16) -----------
// block 0 additionally builds prefix[0..256]: prefix[b] = sum of clamped
// lengths of rows < b (prefix[256] = sumL).
__global__ void pack_kernel(const float* __restrict__ Wf, const float* __restrict__ Wb,
                            const float* __restrict__ Whf, const float* __restrict__ Whb,
                            const float* __restrict__ emb,
                            const int* __restrict__ seq_len,
                            unsigned short* __restrict__ Wp, unsigned short* __restrict__ Whp,
                            unsigned short* __restrict__ Ep, int* __restrict__ prefix,
                            float* __restrict__ out) {
    int blk = blockIdx.x;
    int k = threadIdx.x;
    if (blk == 0) {
        __shared__ int sc[257];
        if (k == 0) { sc[0] = 0; out[0] = 0.0f; }   // zero accumulator for crf atomicAdd
        if (k < 256) sc[k + 1] = min(max(seq_len[k], 1), T_);
        __syncthreads();
        #pragma unroll 1
        for (int off = 1; off < 257; off <<= 1) {
            int v = (k >= off && k < 257) ? sc[k - off] : 0;
            __syncthreads();
            if (k < 257) sc[k] += v;
            __syncthreads();
        }
        if (k < 257) prefix[k] = sc[k];
    }
    if (blk < NG) {
        float v = 0.0f;
        if (k < E_) v = (blk < G4) ? Wf[blk * E_ + k] : Wb[(blk - G4) * E_ + k];
        Wp[blk * KP + k] = f2bf(v);
    } else if (blk < NG + 1024) {
        // W_hh -> bf16 fragment order: Whp[(((d*8+w)*4+j)*4+kc)*64 + lane]*8 + e
        int t = blk - NG;
        int d = t >> 9, g = t & 511;
        if (k < H_) {
            const float* src = d ? Whb : Whf;
            float v = src[g * H_ + k];
            int w = (g >> 4) & 7, j = g >> 7, colq = g & 15;
            int kc = k >> 5, quad = (k >> 3) & 3, e = k & 7;
            Whp[((((size_t)(d * 8 + w) * 4 + j) * 4 + kc) * 64 + quad * 16 + colq) * 8 + e] = f2bf(v);
        }
    } else {
        int r = blk - NG - 1024;             // vocab row 0..V_-1
        float v = (k < E_) ? emb[(size_t)r * E_ + k] : 0.0f;
        Ep[(size_t)r * KP + k] = f2bf(v);
    }
}

// ---------------- bf16 MFMA GEMM: gx = emb[sent] @ W^T + bias, permuted ------
// M-dimension is length-compacted: row ci in [0,sumL) maps to (b,t) via the
// prefix array (binary search in LDS). Blocks beyond sumL exit immediately.
// Grid is a 1-D bijection of (y,bx) chosen so the 8 bx-blocks of one y-tile
// (same A panel) land on the SAME XCD: id = slot*8 + xcd, y = 8*(slot>>3) +
// xcd, bx = slot&7 -> for fixed y, xcd = y&7 and bx spans consecutive slots.
__global__ __launch_bounds__(256, 3) void gemm_kernel(const unsigned short* __restrict__ Ep,
                                                      const int* __restrict__ sent,
                                                      const unsigned short* __restrict__ Bw,
                                                      const float* __restrict__ bF,
                                                      const float* __restrict__ bB,
                                                      const int* __restrict__ prefix,
                                                      unsigned short* __restrict__ C) {
    __shared__ __align__(16) unsigned short As[128 * 64];
    __shared__ __align__(16) unsigned short Bs[128 * 64];
    __shared__ int pfx[257];
    const int tid  = threadIdx.x;
    for (int i = tid; i < 257; i += 256) pfx[i] = prefix[i];
    __syncthreads();
    const int sumL = pfx[256];
    const int bid  = blockIdx.x;
    const int xcd  = bid & 7;
    const int slot = bid >> 3;
    const int y    = ((slot >> 3) << 3) + xcd;   // 8*(slot/8) + xcd
    const int bx   = slot & 7;
    const int mBase = y * 128;
    if (mBase >= sumL) return;
    const int lane = tid & 63;
    const int wave = tid >> 6;
    const int wr = wave >> 1, wc = wave & 1;
    const int colL = lane & 15;
    const int d  = bx >> 2;
    const int w0 = (bx & 3) * 2;
    int toks[4];
    #pragma unroll
    for (int j = 0; j < 4; j++) {
        int ci = mBase + ((tid + 256 * j) >> 3);
        ci = min(ci, sumL - 1);
        int lo = 0, hi = 256;            // largest b with pfx[b] <= ci  (8 steps)
        #pragma unroll
        for (int it = 0; it < 8; it++) {
            int mid = (lo + hi) >> 1;
            if (pfx[mid] <= ci) lo = mid; else hi = mid;
        }
        toks[j] = sent[lo * T_ + (ci - pfx[lo])];
    }
    f32x4 acc[4][4] = {};
    for (int k0 = 0; k0 < KP; k0 += 64) {
        #pragma unroll
        for (int j = 0; j < 4; j++) {
            int c   = tid + 256 * j;       // 16B chunk id 0..1023; LDS offset = c*16
            int col = (c & 7) * 8;
            __builtin_amdgcn_global_load_lds(
                (const void*)(Ep + (size_t)toks[j] * KP + k0 + col),
                (void*)((char*)As + c * 16), 16, 0, 0);
            int row = c >> 3;
            int ws = row >> 6, jj = (row >> 4) & 3, cc = row & 15;
            int srcrow = d * 512 + (8 * jj + w0 + ws) * 16 + cc;
            __builtin_amdgcn_global_load_lds(
                (const void*)(Bw + (size_t)srcrow * KP + k0 + col),
                (void*)((char*)Bs + c * 16), 16, 0, 0);
        }
        __syncthreads();
        #pragma unroll
        for (int ks = 0; ks < 2; ks++) {
            bf16x8 af[4], bfr[4];
            #pragma unroll
            for (int i = 0; i < 4; i++) {
                int arow = wr * 64 + i * 16 + colL;
                af[i]  = *(const bf16x8*)(As + arow * 64 + ks * 32 + (lane >> 4) * 8);
                int brow = wc * 64 + i * 16 + colL;
                bfr[i] = *(const bf16x8*)(Bs + brow * 64 + ks * 32 + (lane >> 4) * 8);
            }
            #pragma unroll
            for (int i = 0; i < 4; i++)
                #pragma unroll
                for (int n2 = 0; n2 < 4; n2++)
                    acc[i][n2] = __builtin_amdgcn_mfma_f32_16x16x32_bf16(af[i], bfr[n2], acc[i][n2], 0, 0, 0);
        }
        __syncthreads();
    }
    const float* bias_d = d ? bB : bF;
    float bj[4];
    #pragma unroll
    for (int n2 = 0; n2 < 4; n2++) bj[n2] = bias_d[(8 * n2 + w0 + wc) * 16 + colL];
    #pragma unroll
    for (int i = 0; i < 4; i++)
        #pragma unroll
        for (int r = 0; r < 4; r++) {
            int row = mBase + wr * 64 + i * 16 + (lane >> 4) * 4 + r;
            if (row < sumL) {
                u16x4 v;
                #pragma unroll
                for (int n2 = 0; n2 < 4; n2++) v[n2] = f2bf(acc[i][n2][r] + bj[n2]);
                *(u16x4*)(C + (size_t)row * NG + d * 512 + (w0 + wc) * 64 + colL * 4) = v;
            }
        }
}

// ---------------- MFMA LSTM recurrence + feats projection --------------------
// grid 128: block = (4 batch rows, dir). 576 threads = 9 waves (R7 structure).
// gx is length-compacted: step t of row lives at (prefix[row]+t)*NG.
// R17: per-gate MFMA chain = two independent 2-deep chains from a persistent
// zero C operand; gx seed added as a scalar at the end.
__global__ __launch_bounds__(576, 1) void lstm_kernel(const unsigned short* __restrict__ gxP,
                                                      const unsigned short* __restrict__ Whp,
                                                      const int* __restrict__ seq_len,
                                                      const int* __restrict__ prefix,
                                                      const float* __restrict__ Wfc,
                                                      float* __restrict__ featsF,
                                                      float* __restrict__ featsB) {
    __shared__ __align__(16) unsigned short hL[2][16 * HSTR];
    __shared__ int Ls[4];
    __shared__ int Ps[4];
    __shared__ int maxLs;
    const int tid  = threadIdx.x;
    const int wave = tid >> 6;
    const int lane = tid & 63;
    const int col  = lane & 15;
    const int quad = lane >> 4;
    const int dir  = blockIdx.x & 1;
    const int b0   = (blockIdx.x >> 1) * 4;
    float* fOut = dir ? featsB : featsF;

    if (tid < 4) {
        Ls[tid] = min(max(seq_len[b0 + tid], 1), T_);
        Ps[tid] = prefix[b0 + tid];
    }
    __syncthreads();
    if (tid == 0) { int m = 0; for (int i = 0; i < 4; i++) m = max(m, Ls[i]); maxLs = m; }
    __syncthreads();
    const int maxL = maxLs;
    const int Lq = Ls[quad];              // this lane's row length
    const int dNG = dir ? -NG : NG;

    bf16x8 Bf[4][4];                      // W_hh fragments (waves 0-7)
    bf16x8 Wf8[4];                        // W_fc fragments (wave 8)
    const unsigned short* rb = nullptr;   // this lane's gx base (step-0 pos)
    int ofs2 = 0;                         // element offset of the step-(s+2) load
    u16x4 gx0v = {}, gx1v = {};           // parity prefetch slots
    float* fb = nullptr;                  // wave-8 feats store base
    int foff = 0;

    if (wave < 8) {
        #pragma unroll
        for (int j = 0; j < 4; j++)
            #pragma unroll
            for (int kc = 0; kc < 4; kc++)
                Bf[j][kc] = *(const bf16x8*)(Whp +
                    ((((size_t)(dir * 8 + wave) * 4 + j) * 4 + kc) * 64 + lane) * 8);
        int p0 = dir ? (Lq - 1) : 0;
        rb = gxP + ((size_t)(Ps[quad] + p0)) * NG + dir * 512 + wave * 64 + col * 4;
        gx0v = *(const u16x4*)(rb);
        gx1v = *(const u16x4*)(rb + ((Lq > 1) ? dNG : 0));
        ofs2 = min(2, Lq - 1) * dNG;
    } else {
        #pragma unroll
        for (int kc = 0; kc < 4; kc++)
            #pragma unroll
            for (int e = 0; e < 8; e++) {
                float v = (col < NT_) ? Wfc[col * 256 + dir * H_ + kc * 32 + quad * 8 + e] : 0.0f;
                Wf8[kc][e] = (short)f2bf(v);
            }
        fb = fOut + (size_t)(b0 + quad) * T_ * NT_ + col;
        foff = (dir ? (Lq - 1) : 0) * NT_;
    }
    const int fd = dir ? -NT_ : NT_;

    float cst = 0.0f;
    bf16x8 Af[4];
    #pragma unroll
    for (int kc = 0; kc < 4; kc++)
        #pragma unroll
        for (int e = 0; e < 8; e++) Af[kc][e] = 0;   // h(-1) = 0

    const f32x4 zv = {0.f, 0.f, 0.f, 0.f};           // persistent zero C operand

    auto step_body = [&](int s, u16x4& gxs, int par) {
        if (wave < 8) {
            float seed[4];
            #pragma unroll
            for (int j = 0; j < 4; j++) seed[j] = bf2f(gxs[j]);
            // prefetch gx for step s+2 into the slot just consumed
            gxs = *(const u16x4*)(rb + ofs2);
            ofs2 = (s + 3 < Lq) ? ofs2 + dNG : ofs2;
            f32x4 accA[4], accB[4];
            #pragma unroll
            for (int j = 0; j < 4; j++) {
                accA[j] = __builtin_amdgcn_mfma_f32_16x16x32_bf16(Af[0], Bf[j][0], zv, 0, 0, 0);
                accB[j] = __builtin_amdgcn_mfma_f32_16x16x32_bf16(Af[2], Bf[j][2], zv, 0, 0, 0);
            }
            #pragma unroll
            for (int j = 0; j < 4; j++) {
                accA[j] = __builtin_amdgcn_mfma_f32_16x16x32_bf16(Af[1], Bf[j][1], accA[j], 0, 0, 0);
                accB[j] = __builtin_amdgcn_mfma_f32_16x16x32_bf16(Af[3], Bf[j][3], accB[j], 0, 0, 0);
            }
            float g0 = (accA[0][0] + accB[0][0]) + seed[0];
            float g1 = (accA[1][0] + accB[1][0]) + seed[1];
            float g2 = (accA[2][0] + accB[2][0]) + seed[2];
            float g3 = (accA[3][0] + accB[3][0]) + seed[3];
            float cn = sigf(g1) * cst + sigf(g0) * tanhfast(g2);
            cst = cn;
            float hn = sigf(g3) * tanhfast(cn);
            hL[par][(quad * 4) * HSTR + wave * 16 + col] = f2bf(hn);
        }
        barrier_lgkm();
        #pragma unroll
        for (int kc = 0; kc < 4; kc++)
            Af[kc] = *(const bf16x8*)(&hL[par][col * HSTR + kc * 32 + quad * 8]);
        if (wave == 8) {
            f32x4 fcA = __builtin_amdgcn_mfma_f32_16x16x32_bf16(Af[0], Wf8[0], zv, 0, 0, 0);
            f32x4 fcB = __builtin_amdgcn_mfma_f32_16x16x32_bf16(Af[2], Wf8[2], zv, 0, 0, 0);
            fcA = __builtin_amdgcn_mfma_f32_16x16x32_bf16(Af[1], Wf8[1], fcA, 0, 0, 0);
            fcB = __builtin_amdgcn_mfma_f32_16x16x32_bf16(Af[3], Wf8[3], fcB, 0, 0, 0);
            if (col < NT_ && s < Lq) fb[foff] = fcA[0] + fcB[0];
            foff += fd;
        }
    };

    for (int s = 0; s < maxL; s += 2) {
        step_body(s, gx0v, 0);
        if (s + 1 < maxL) step_body(s + 1, gx1v, 1);
    }
}

// ---------------- CRF: one wave per batch row, fused mean --------------------
// Alpha lives in a register (lane j owns alpha_j); redistribution via 13
// readlane broadcasts per step (SGPR path, no ds_bpermute) -- no LDS, no
// barriers on the recurrence path. Max tree in v_max3 triples (exact).
// Feats staged one 16-step chunk ahead via float4 bulk loads (lanes 0..51).
__global__ __launch_bounds__(64) void crf_kernel(const float* __restrict__ fF,
                                                 const float* __restrict__ fB,
                                                 const float* __restrict__ bfc,
                                                 const float* __restrict__ trans,
                                                 const int* __restrict__ tags,
                                                 const int* __restrict__ seq_len,
                                                 float* __restrict__ out) {
    __shared__ __align__(16) float feat_lds[2 * 208];
    __shared__ float Tlds[NT_ * NT_];
    const int lane = threadIdx.x;
    const int b = blockIdx.x;
    const int Lb = min(max(seq_len[b], 1), T_);
    const float* fFb = fF + (size_t)b * T_ * NT_;
    const float* fBb = fB + (size_t)b * T_ * NT_;
    const int* tg = tags + (size_t)b * T_;

    for (int i = lane; i < NT_ * NT_; i += 64) Tlds[i] = trans[i];

    const int jc = min(lane, NT_ - 1);
    float Tj[NT_];
    #pragma unroll
    for (int i = 0; i < NT_; i++) Tj[i] = trans[jc * NT_ + i];
    const float bj  = bfc[jc];
    const float T10 = trans[10 * NT_ + jc];
    float alj = (jc == 0 && lane == 0) ? 0.0f : NEGV;   // alpha_j in-register

    // stage chunk 0
    const int e0 = lane * 4;
    const bool ldact = (lane < 52);
    float4 vF = {}, vB = {};
    if (ldact) { vF = *(const float4*)(fFb + e0); vB = *(const float4*)(fBb + e0); }

    #pragma unroll 1
    for (int c = 0; c < 12; ++c) {
        if (ldact) {
            float4 w;
            #pragma unroll
            for (int k = 0; k < 4; k++) {
                unsigned g = (unsigned)(c * 208 + e0 + k);
                unsigned t = g / 13u;
                float s = ((const float*)&vF)[k] + ((const float*)&vB)[k];
                ((float*)&w)[k] = (t < (unsigned)Lb) ? s : 0.0f;
            }
            *(float4*)&feat_lds[(c & 1) * 208 + e0] = w;
            if (c < 11) {
                vF = *(const float4*)(fFb + (c + 1) * 208 + e0);
                vB = *(const float4*)(fBb + (c + 1) * 208 + e0);
            }
        }
        barrier_lgkm();   // WAR on the other buffer protected one chunk later
        const int fbase = (c & 1) * 208;
        for (int tt = 0; tt < 16; ++tt) {
            float a0  = bcast(alj, 0),  a1  = bcast(alj, 1);
            float a2  = bcast(alj, 2),  a3  = bcast(alj, 3);
            float a4  = bcast(alj, 4),  a5  = bcast(alj, 5);
            float a6  = bcast(alj, 6),  a7  = bcast(alj, 7);
            float a8  = bcast(alj, 8),  a9  = bcast(alj, 9);
            float a10 = bcast(alj, 10), a11 = bcast(alj, 11);
            float a12 = bcast(alj, 12);
            float feat = feat_lds[fbase + tt * NT_ + jc];
            float v0 = a0 + Tj[0],  v1 = a1 + Tj[1],  v2 = a2 + Tj[2],  v3 = a3 + Tj[3];
            float v4 = a4 + Tj[4],  v5 = a5 + Tj[5],  v6 = a6 + Tj[6],  v7 = a7 + Tj[7];
            float v8 = a8 + Tj[8],  v9 = a9 + Tj[9],  v10 = a10 + Tj[10], v11 = a11 + Tj[11];
            float v12 = a12 + Tj[12];
            // max tree as v_max3 triples (exact, depth 3)
            float mA = fmaxf(fmaxf(v0, v1), v2);
            float mB = fmaxf(fmaxf(v3, v4), v5);
            float mC = fmaxf(fmaxf(v6, v7), v8);
            float mD = fmaxf(fmaxf(v9, v10), v11);
            float m  = fmaxf(fmaxf(mA, mB), fmaxf(fmaxf(mC, mD), v12));
            float e0_ = __expf(v0 - m),  e1_ = __expf(v1 - m),  e2_ = __expf(v2 - m);
            float e3_ = __expf(v3 - m),  e4_ = __expf(v4 - m),  e5_ = __expf(v5 - m);
            float e6_ = __expf(v6 - m),  e7_ = __expf(v7 - m),  e8_ = __expf(v8 - m);
            float e9_ = __expf(v9 - m),  e10_ = __expf(v10 - m), e11_ = __expf(v11 - m);
            float e12_ = __expf(v12 - m);
            float s0 = e0_ + e1_, s1 = e2_ + e3_, s2 = e4_ + e5_, s3 = e6_ + e7_;
            float s4 = e8_ + e9_, s5 = e10_ + e11_;
            float u0 = s0 + s1, u1 = s2 + s3, u2 = s4 + s5;
            float ss = (u0 + u1) + (u2 + e12_);
            alj = m + __logf(ss) + feat + bj;
        }
    }

    // gold score: t = lane, lane+64, lane+128
    float gp = 0.0f;
    #pragma unroll
    for (int u = 0; u < 3; ++u) {
        int t = lane + u * 64;
        int tt_ = tg[t];
        int pv = (t == 0) ? 0 : tg[t - 1];
        float e = bfc[tt_];
        if (t < Lb) e += fFb[t * NT_ + tt_] + fBb[t * NT_ + tt_];
        gp += Tlds[tt_ * NT_ + pv] + e;
    }
    #pragma unroll
    for (int o = 32; o > 0; o >>= 1) gp += __shfl_down(gp, o, 64);

    // fwd = LSE_j(alphaT[j] + trans[10][j])
    float vj = (lane < NT_) ? (alj + T10) : -3.0e38f;
    float mm = vj;
    #pragma unroll
    for (int o = 32; o > 0; o >>= 1) mm = fmaxf(mm, __shfl_down(mm, o, 64));
    mm = __shfl(mm, 0, 64);
    float se = (lane < NT_) ? __expf(vj - mm) : 0.0f;
    #pragma unroll
    for (int o = 32; o > 0; o >>= 1) se += __shfl_down(se, o, 64);
    if (lane == 0) {
        float fwd = mm + __logf(se);
        float gold = gp + Tlds[10 * NT_ + tg[T_ - 1]];
        atomicAdd(out, (fwd - gold) * (1.0f / 256.0f));
    }
}

extern "C" void kernel_launch(void* const* d_in, const int* in_sizes, int n_in,
                              void* d_out, int out_size, void* d_ws, size_t ws_size,
                              hipStream_t stream) {
    const int*   sentence  = (const int*)d_in[0];
    const int*   seq_len   = (const int*)d_in[1];
    const int*   tags      = (const int*)d_in[2];
    const float* embedding = (const float*)d_in[3];
    const float* W_ih_f    = (const float*)d_in[4];
    const float* W_hh_f    = (const float*)d_in[5];
    const float* b_f       = (const float*)d_in[6];
    const float* W_ih_b    = (const float*)d_in[7];
    const float* W_hh_b    = (const float*)d_in[8];
    const float* b_b       = (const float*)d_in[9];
    const float* W_fc      = (const float*)d_in[10];
    const float* b_fc      = (const float*)d_in[11];
    const float* trans     = (const float*)d_in[12];
    float* out = (float*)d_out;

    char* ws = (char*)d_ws;
    const size_t M = (size_t)B_ * T_;                   // 49152
    unsigned short* Wp  = (unsigned short*)(ws);                         // 655,360
    unsigned short* Ep  = (unsigned short*)(ws + 655360);                // 11626*320*2 = 7,440,640
    unsigned short* gx  = (unsigned short*)(ws + 8096000);               // 100,663,296
    float* featsF = (float*)(ws + 108759296);                            // 2,555,904
    float* featsB = (float*)(ws + 111315200);                            // 2,555,904
    unsigned short* Whp = (unsigned short*)(ws + 113871104);             // 262,144
    int* prefix = (int*)(ws + 114133248);                                // 257*4 = 1,028

    pack_kernel<<<NG + 1024 + V_, KP, 0, stream>>>(W_ih_f, W_ih_b, W_hh_f, W_hh_b,
                                                   embedding, seq_len, Wp, Whp, Ep, prefix, out);
    gemm_kernel<<<(int)(M / 128) * 8, 256, 0, stream>>>(Ep, sentence, Wp, b_f, b_b, prefix, gx);
    lstm_kernel<<<128, 576, 0, stream>>>(gx, Whp, seq_len, prefix, W_fc, featsF, featsB);
    crf_kernel<<<B_, 64, 0, stream>>>(featsF, featsB, b_fc, trans, tags, seq_len, out);
}

// Round 5
// 278.321 us; speedup vs baseline: 1.8449x; 1.0060x over previous
//
#include <hip/hip_runtime.h>
#include <hip/hip_bf16.h>

// BiLSTM-CRF fused pipeline for MI355X (gfx950).
// R18: best-of composition + micro-trims.
//  - lstm: REVERTED to R16 step (4-deep MFMA chain seeded with gx in acc[0]).
//    R17's 2x2-deep flatten regressed ~1.2us (lstm is not MFMA-latency-bound;
//    step is ~68% SIMD-issue-busy, mixed issue+LDS/barrier latency).
//  - crf: R17 readlane broadcasts + max3 tree KEPT (measured ~-6us); staging
//    mask now uses the linear-element boundary (g < Lb*13) instead of a
//    per-element magic-divide -- exact same predicate, ~150 fewer VALU ops.
//  - gemm/pack: R16 (length-compacted + XCD-swizzled grid) unchanged.

#define B_   256
#define T_   192
#define E_   300
#define KP   320   // padded K
#define V_   11626
#define H_   128
#define G4   512   // 4*H
#define NG   1024  // both directions
#define NT_  13
#define NEGV -10000.0f
#define HSTR 144   // hL row stride in ushorts (288B, 16B-aligned)

typedef __attribute__((ext_vector_type(8))) short bf16x8;
typedef __attribute__((ext_vector_type(4))) float f32x4;
typedef __attribute__((ext_vector_type(4))) unsigned short u16x4;

__device__ __forceinline__ unsigned short f2bf(float f) {
    return (unsigned short)(__float_as_uint(f) >> 16);   // truncation: ample threshold
}
__device__ __forceinline__ float bf2f(unsigned short h) {
    return __uint_as_float(((unsigned)h) << 16);
}
__device__ __forceinline__ float sigf(float x) {
    return __builtin_amdgcn_rcpf(1.0f + __expf(-x));
}
__device__ __forceinline__ float tanhfast(float x) {
    return __builtin_amdgcn_rcpf(1.0f + __expf(-2.0f * x)) * 2.0f - 1.0f;
}
__device__ __forceinline__ float bcast(float v, int lane) {
    return __uint_as_float(__builtin_amdgcn_readlane(__float_as_uint(v), lane));
}
__device__ __forceinline__ void barrier_lgkm() {
    // LDS-visibility barrier WITHOUT the forced vmcnt(0) drain of __syncthreads
    asm volatile("s_waitcnt lgkmcnt(0)\n\ts_barrier" ::: "memory");
}

// ------- pack W_ih + W_hh (frag order) + emb table (K-padded bf16) -----------
// block 0 additionally builds prefix[0..256]: prefix[b] = sum of clamped
// lengths of rows < b (prefix[256] = sumL).
__global__ void pack_kernel(const float* __restrict__ Wf, const float* __restrict__ Wb,
                            const float* __restrict__ Whf, const float* __restrict__ Whb,
                            const float* __restrict__ emb,
                            const int* __restrict__ seq_len,
                            unsigned short* __restrict__ Wp, unsigned short* __restrict__ Whp,
                            unsigned short* __restrict__ Ep, int* __restrict__ prefix,
                            float* __restrict__ out) {
    int blk = blockIdx.x;
    int k = threadIdx.x;
    if (blk == 0) {
        __shared__ int sc[257];
        if (k == 0) { sc[0] = 0; out[0] = 0.0f; }   // zero accumulator for crf atomicAdd
        if (k < 256) sc[k + 1] = min(max(seq_len[k], 1), T_);
        __syncthreads();
        #pragma unroll 1
        for (int off = 1; off < 257; off <<= 1) {
            int v = (k >= off && k < 257) ? sc[k - off] : 0;
            __syncthreads();
            if (k < 257) sc[k] += v;
            __syncthreads();
        }
        if (k < 257) prefix[k] = sc[k];
    }
    if (blk < NG) {
        float v = 0.0f;
        if (k < E_) v = (blk < G4) ? Wf[blk * E_ + k] : Wb[(blk - G4) * E_ + k];
        Wp[blk * KP + k] = f2bf(v);
    } else if (blk < NG + 1024) {
        // W_hh -> bf16 fragment order: Whp[(((d*8+w)*4+j)*4+kc)*64 + lane]*8 + e
        int t = blk - NG;
        int d = t >> 9, g = t & 511;
        if (k < H_) {
            const float* src = d ? Whb : Whf;
            float v = src[g * H_ + k];
            int w = (g >> 4) & 7, j = g >> 7, colq = g & 15;
            int kc = k >> 5, quad = (k >> 3) & 3, e = k & 7;
            Whp[((((size_t)(d * 8 + w) * 4 + j) * 4 + kc) * 64 + quad * 16 + colq) * 8 + e] = f2bf(v);
        }
    } else {
        int r = blk - NG - 1024;             // vocab row 0..V_-1
        float v = (k < E_) ? emb[(size_t)r * E_ + k] : 0.0f;
        Ep[(size_t)r * KP + k] = f2bf(v);
    }
}

// ---------------- bf16 MFMA GEMM: gx = emb[sent] @ W^T + bias, permuted ------
// M-dimension is length-compacted: row ci in [0,sumL) maps to (b,t) via the
// prefix array (binary search in LDS). Blocks beyond sumL exit immediately.
// Grid is a 1-D bijection of (y,bx) chosen so the 8 bx-blocks of one y-tile
// (same A panel) land on the SAME XCD: id = slot*8 + xcd, y = 8*(slot>>3) +
// xcd, bx = slot&7 -> for fixed y, xcd = y&7 and bx spans consecutive slots.
__global__ __launch_bounds__(256, 3) void gemm_kernel(const unsigned short* __restrict__ Ep,
                                                      const int* __restrict__ sent,
                                                      const unsigned short* __restrict__ Bw,
                                                      const float* __restrict__ bF,
                                                      const float* __restrict__ bB,
                                                      const int* __restrict__ prefix,
                                                      unsigned short* __restrict__ C) {
    __shared__ __align__(16) unsigned short As[128 * 64];
    __shared__ __align__(16) unsigned short Bs[128 * 64];
    __shared__ int pfx[257];
    const int tid  = threadIdx.x;
    for (int i = tid; i < 257; i += 256) pfx[i] = prefix[i];
    __syncthreads();
    const int sumL = pfx[256];
    const int bid  = blockIdx.x;
    const int xcd  = bid & 7;
    const int slot = bid >> 3;
    const int y    = ((slot >> 3) << 3) + xcd;   // 8*(slot/8) + xcd
    const int bx   = slot & 7;
    const int mBase = y * 128;
    if (mBase >= sumL) return;
    const int lane = tid & 63;
    const int wave = tid >> 6;
    const int wr = wave >> 1, wc = wave & 1;
    const int colL = lane & 15;
    const int d  = bx >> 2;
    const int w0 = (bx & 3) * 2;
    int toks[4];
    #pragma unroll
    for (int j = 0; j < 4; j++) {
        int ci = mBase + ((tid + 256 * j) >> 3);
        ci = min(ci, sumL - 1);
        int lo = 0, hi = 256;            // largest b with pfx[b] <= ci  (8 steps)
        #pragma unroll
        for (int it = 0; it < 8; it++) {
            int mid = (lo + hi) >> 1;
            if (pfx[mid] <= ci) lo = mid; else hi = mid;
        }
        toks[j] = sent[lo * T_ + (ci - pfx[lo])];
    }
    f32x4 acc[4][4] = {};
    for (int k0 = 0; k0 < KP; k0 += 64) {
        #pragma unroll
        for (int j = 0; j < 4; j++) {
            int c   = tid + 256 * j;       // 16B chunk id 0..1023; LDS offset = c*16
            int col = (c & 7) * 8;
            __builtin_amdgcn_global_load_lds(
                (const void*)(Ep + (size_t)toks[j] * KP + k0 + col),
                (void*)((char*)As + c * 16), 16, 0, 0);
            int row = c >> 3;
            int ws = row >> 6, jj = (row >> 4) & 3, cc = row & 15;
            int srcrow = d * 512 + (8 * jj + w0 + ws) * 16 + cc;
            __builtin_amdgcn_global_load_lds(
                (const void*)(Bw + (size_t)srcrow * KP + k0 + col),
                (void*)((char*)Bs + c * 16), 16, 0, 0);
        }
        __syncthreads();
        #pragma unroll
        for (int ks = 0; ks < 2; ks++) {
            bf16x8 af[4], bfr[4];
            #pragma unroll
            for (int i = 0; i < 4; i++) {
                int arow = wr * 64 + i * 16 + colL;
                af[i]  = *(const bf16x8*)(As + arow * 64 + ks * 32 + (lane >> 4) * 8);
                int brow = wc * 64 + i * 16 + colL;
                bfr[i] = *(const bf16x8*)(Bs + brow * 64 + ks * 32 + (lane >> 4) * 8);
            }
            #pragma unroll
            for (int i = 0; i < 4; i++)
                #pragma unroll
                for (int n2 = 0; n2 < 4; n2++)
                    acc[i][n2] = __builtin_amdgcn_mfma_f32_16x16x32_bf16(af[i], bfr[n2], acc[i][n2], 0, 0, 0);
        }
        __syncthreads();
    }
    const float* bias_d = d ? bB : bF;
    float bj[4];
    #pragma unroll
    for (int n2 = 0; n2 < 4; n2++) bj[n2] = bias_d[(8 * n2 + w0 + wc) * 16 + colL];
    #pragma unroll
    for (int i = 0; i < 4; i++)
        #pragma unroll
        for (int r = 0; r < 4; r++) {
            int row = mBase + wr * 64 + i * 16 + (lane >> 4) * 4 + r;
            if (row < sumL) {
                u16x4 v;
                #pragma unroll
                for (int n2 = 0; n2 < 4; n2++) v[n2] = f2bf(acc[i][n2][r] + bj[n2]);
                *(u16x4*)(C + (size_t)row * NG + d * 512 + (w0 + wc) * 64 + colL * 4) = v;
            }
        }
}

// ---------------- MFMA LSTM recurrence + feats projection --------------------
// grid 128: block = (4 batch rows, dir). 576 threads = 9 waves (R7 structure).
// gx is length-compacted: step t of row lives at (prefix[row]+t)*NG.
// R18: step body is the R16 form (4-deep seeded chain -- measured best).
__global__ __launch_bounds__(576, 1) void lstm_kernel(const unsigned short* __restrict__ gxP,
                                                      const unsigned short* __restrict__ Whp,
                                                      const int* __restrict__ seq_len,
                                                      const int* __restrict__ prefix,
                                                      const float* __restrict__ Wfc,
                                                      float* __restrict__ featsF,
                                                      float* __restrict__ featsB) {
    __shared__ __align__(16) unsigned short hL[2][16 * HSTR];
    __shared__ int Ls[4];
    __shared__ int Ps[4];
    __shared__ int maxLs;
    const int tid  = threadIdx.x;
    const int wave = tid >> 6;
    const int lane = tid & 63;
    const int col  = lane & 15;
    const int quad = lane >> 4;
    const int dir  = blockIdx.x & 1;
    const int b0   = (blockIdx.x >> 1) * 4;
    float* fOut = dir ? featsB : featsF;

    if (tid < 4) {
        Ls[tid] = min(max(seq_len[b0 + tid], 1), T_);
        Ps[tid] = prefix[b0 + tid];
    }
    __syncthreads();
    if (tid == 0) { int m = 0; for (int i = 0; i < 4; i++) m = max(m, Ls[i]); maxLs = m; }
    __syncthreads();
    const int maxL = maxLs;
    const int Lq = Ls[quad];              // this lane's row length
    const int dNG = dir ? -NG : NG;

    bf16x8 Bf[4][4];                      // W_hh fragments (waves 0-7)
    bf16x8 Wf8[4];                        // W_fc fragments (wave 8)
    const unsigned short* rb = nullptr;   // this lane's gx base (step-0 pos)
    int ofs2 = 0;                         // element offset of the step-(s+2) load
    u16x4 gx0v = {}, gx1v = {};           // parity prefetch slots
    float* fb = nullptr;                  // wave-8 feats store base
    int foff = 0;

    if (wave < 8) {
        #pragma unroll
        for (int j = 0; j < 4; j++)
            #pragma unroll
            for (int kc = 0; kc < 4; kc++)
                Bf[j][kc] = *(const bf16x8*)(Whp +
                    ((((size_t)(dir * 8 + wave) * 4 + j) * 4 + kc) * 64 + lane) * 8);
        int p0 = dir ? (Lq - 1) : 0;
        rb = gxP + ((size_t)(Ps[quad] + p0)) * NG + dir * 512 + wave * 64 + col * 4;
        gx0v = *(const u16x4*)(rb);
        gx1v = *(const u16x4*)(rb + ((Lq > 1) ? dNG : 0));
        ofs2 = min(2, Lq - 1) * dNG;
    } else {
        #pragma unroll
        for (int kc = 0; kc < 4; kc++)
            #pragma unroll
            for (int e = 0; e < 8; e++) {
                float v = (col < NT_) ? Wfc[col * 256 + dir * H_ + kc * 32 + quad * 8 + e] : 0.0f;
                Wf8[kc][e] = (short)f2bf(v);
            }
        fb = fOut + (size_t)(b0 + quad) * T_ * NT_ + col;
        foff = (dir ? (Lq - 1) : 0) * NT_;
    }
    const int fd = dir ? -NT_ : NT_;

    float cst = 0.0f;
    bf16x8 Af[4];
    #pragma unroll
    for (int kc = 0; kc < 4; kc++)
        #pragma unroll
        for (int e = 0; e < 8; e++) Af[kc][e] = 0;   // h(-1) = 0

    auto step_body = [&](int s, u16x4& gxs, int par) {
        if (wave < 8) {
            f32x4 acc[4];
            #pragma unroll
            for (int j = 0; j < 4; j++) {
                acc[j][0] = bf2f(gxs[j]);            // gx (+bias) seed, real row
                acc[j][1] = 0.f; acc[j][2] = 0.f; acc[j][3] = 0.f;
            }
            // prefetch gx for step s+2 into the slot just consumed
            gxs = *(const u16x4*)(rb + ofs2);
            ofs2 = (s + 3 < Lq) ? ofs2 + dNG : ofs2;
            #pragma unroll
            for (int kc = 0; kc < 4; kc++)
                #pragma unroll
                for (int j = 0; j < 4; j++)
                    acc[j] = __builtin_amdgcn_mfma_f32_16x16x32_bf16(Af[kc], Bf[j][kc], acc[j], 0, 0, 0);
            float cn = sigf(acc[1][0]) * cst + sigf(acc[0][0]) * tanhfast(acc[2][0]);
            cst = cn;
            float hn = sigf(acc[3][0]) * tanhfast(cn);
            hL[par][(quad * 4) * HSTR + wave * 16 + col] = f2bf(hn);
        }
        barrier_lgkm();
        #pragma unroll
        for (int kc = 0; kc < 4; kc++)
            Af[kc] = *(const bf16x8*)(&hL[par][col * HSTR + kc * 32 + quad * 8]);
        if (wave == 8) {
            f32x4 fc = (f32x4){0.f, 0.f, 0.f, 0.f};
            #pragma unroll
            for (int kc = 0; kc < 4; kc++)
                fc = __builtin_amdgcn_mfma_f32_16x16x32_bf16(Af[kc], Wf8[kc], fc, 0, 0, 0);
            if (col < NT_ && s < Lq) fb[foff] = fc[0];
            foff += fd;
        }
    };

    for (int s = 0; s < maxL; s += 2) {
        step_body(s, gx0v, 0);
        if (s + 1 < maxL) step_body(s + 1, gx1v, 1);
    }
}

// ---------------- CRF: one wave per batch row, fused mean --------------------
// Alpha lives in a register (lane j owns alpha_j); redistribution via 13
// readlane broadcasts per step (SGPR path, no ds_bpermute) -- no LDS, no
// barriers on the recurrence path. Max tree in v_max3 triples (exact).
// Feats staged one 16-step chunk ahead via float4 bulk loads (lanes 0..51);
// padding mask via the linear element boundary g < Lb*13 (exact).
__global__ __launch_bounds__(64) void crf_kernel(const float* __restrict__ fF,
                                                 const float* __restrict__ fB,
                                                 const float* __restrict__ bfc,
                                                 const float* __restrict__ trans,
                                                 const int* __restrict__ tags,
                                                 const int* __restrict__ seq_len,
                                                 float* __restrict__ out) {
    __shared__ __align__(16) float feat_lds[2 * 208];
    __shared__ float Tlds[NT_ * NT_];
    const int lane = threadIdx.x;
    const int b = blockIdx.x;
    const int Lb = min(max(seq_len[b], 1), T_);
    const int eLb = Lb * NT_;             // first padded element index
    const float* fFb = fF + (size_t)b * T_ * NT_;
    const float* fBb = fB + (size_t)b * T_ * NT_;
    const int* tg = tags + (size_t)b * T_;

    for (int i = lane; i < NT_ * NT_; i += 64) Tlds[i] = trans[i];

    const int jc = min(lane, NT_ - 1);
    float Tj[NT_];
    #pragma unroll
    for (int i = 0; i < NT_; i++) Tj[i] = trans[jc * NT_ + i];
    const float bj  = bfc[jc];
    const float T10 = trans[10 * NT_ + jc];
    float alj = (jc == 0 && lane == 0) ? 0.0f : NEGV;   // alpha_j in-register

    // stage chunk 0
    const int e0 = lane * 4;
    const bool ldact = (lane < 52);
    float4 vF = {}, vB = {};
    if (ldact) { vF = *(const float4*)(fFb + e0); vB = *(const float4*)(fBb + e0); }

    #pragma unroll 1
    for (int c = 0; c < 12; ++c) {
        if (ldact) {
            float4 w;
            #pragma unroll
            for (int k = 0; k < 4; k++) {
                int g = c * 208 + e0 + k;
                float s = ((const float*)&vF)[k] + ((const float*)&vB)[k];
                ((float*)&w)[k] = (g < eLb) ? s : 0.0f;
            }
            *(float4*)&feat_lds[(c & 1) * 208 + e0] = w;
            if (c < 11) {
                vF = *(const float4*)(fFb + (c + 1) * 208 + e0);
                vB = *(const float4*)(fBb + (c + 1) * 208 + e0);
            }
        }
        barrier_lgkm();   // WAR on the other buffer protected one chunk later
        const int fbase = (c & 1) * 208;
        for (int tt = 0; tt < 16; ++tt) {
            float a0  = bcast(alj, 0),  a1  = bcast(alj, 1);
            float a2  = bcast(alj, 2),  a3  = bcast(alj, 3);
            float a4  = bcast(alj, 4),  a5  = bcast(alj, 5);
            float a6  = bcast(alj, 6),  a7  = bcast(alj, 7);
            float a8  = bcast(alj, 8),  a9  = bcast(alj, 9);
            float a10 = bcast(alj, 10), a11 = bcast(alj, 11);
            float a12 = bcast(alj, 12);
            float feat = feat_lds[fbase + tt * NT_ + jc];
            float v0 = a0 + Tj[0],  v1 = a1 + Tj[1],  v2 = a2 + Tj[2],  v3 = a3 + Tj[3];
            float v4 = a4 + Tj[4],  v5 = a5 + Tj[5],  v6 = a6 + Tj[6],  v7 = a7 + Tj[7];
            float v8 = a8 + Tj[8],  v9 = a9 + Tj[9],  v10 = a10 + Tj[10], v11 = a11 + Tj[11];
            float v12 = a12 + Tj[12];
            // max tree as v_max3 triples (exact, depth 3)
            float mA = fmaxf(fmaxf(v0, v1), v2);
            float mB = fmaxf(fmaxf(v3, v4), v5);
            float mC = fmaxf(fmaxf(v6, v7), v8);
            float mD = fmaxf(fmaxf(v9, v10), v11);
            float m  = fmaxf(fmaxf(mA, mB), fmaxf(fmaxf(mC, mD), v12));
            float e0_ = __expf(v0 - m),  e1_ = __expf(v1 - m),  e2_ = __expf(v2 - m);
            float e3_ = __expf(v3 - m),  e4_ = __expf(v4 - m),  e5_ = __expf(v5 - m);
            float e6_ = __expf(v6 - m),  e7_ = __expf(v7 - m),  e8_ = __expf(v8 - m);
            float e9_ = __expf(v9 - m),  e10_ = __expf(v10 - m), e11_ = __expf(v11 - m);
            float e12_ = __expf(v12 - m);
            float s0 = e0_ + e1_, s1 = e2_ + e3_, s2 = e4_ + e5_, s3 = e6_ + e7_;
            float s4 = e8_ + e9_, s5 = e10_ + e11_;
            float u0 = s0 + s1, u1 = s2 + s3, u2 = s4 + s5;
            float ss = (u0 + u1) + (u2 + e12_);
            alj = m + __logf(ss) + feat + bj;
        }
    }

    // gold score: t = lane, lane+64, lane+128
    float gp = 0.0f;
    #pragma unroll
    for (int u = 0; u < 3; ++u) {
        int t = lane + u * 64;
        int tt_ = tg[t];
        int pv = (t == 0) ? 0 : tg[t - 1];
        float e = bfc[tt_];
        if (t < Lb) e += fFb[t * NT_ + tt_] + fBb[t * NT_ + tt_];
        gp += Tlds[tt_ * NT_ + pv] + e;
    }
    #pragma unroll
    for (int o = 32; o > 0; o >>= 1) gp += __shfl_down(gp, o, 64);

    // fwd = LSE_j(alphaT[j] + trans[10][j])
    float vj = (lane < NT_) ? (alj + T10) : -3.0e38f;
    float mm = vj;
    #pragma unroll
    for (int o = 32; o > 0; o >>= 1) mm = fmaxf(mm, __shfl_down(mm, o, 64));
    mm = __shfl(mm, 0, 64);
    float se = (lane < NT_) ? __expf(vj - mm) : 0.0f;
    #pragma unroll
    for (int o = 32; o > 0; o >>= 1) se += __shfl_down(se, o, 64);
    if (lane == 0) {
        float fwd = mm + __logf(se);
        float gold = gp + Tlds[10 * NT_ + tg[T_ - 1]];
        atomicAdd(out, (fwd - gold) * (1.0f / 256.0f));
    }
}

extern "C" void kernel_launch(void* const* d_in, const int* in_sizes, int n_in,
                              void* d_out, int out_size, void* d_ws, size_t ws_size,
                              hipStream_t stream) {
    const int*   sentence  = (const int*)d_in[0];
    const int*   seq_len   = (const int*)d_in[1];
    const int*   tags      = (const int*)d_in[2];
    const float* embedding = (const float*)d_in[3];
    const float* W_ih_f    = (const float*)d_in[4];
    const float* W_hh_f    = (const float*)d_in[5];
    const float* b_f       = (const float*)d_in[6];
    const float* W_ih_b    = (const float*)d_in[7];
    const float* W_hh_b    = (const float*)d_in[8];
    const float* b_b       = (const float*)d_in[9];
    const float* W_fc      = (const float*)d_in[10];
    const float* b_fc      = (const float*)d_in[11];
    const float* trans     = (const float*)d_in[12];
    float* out = (float*)d_out;

    char* ws = (char*)d_ws;
    const size_t M = (size_t)B_ * T_;                   // 49152
    unsigned short* Wp  = (unsigned short*)(ws);                         // 655,360
    unsigned short* Ep  = (unsigned short*)(ws + 655360);                // 11626*320*2 = 7,440,640
    unsigned short* gx  = (unsigned short*)(ws + 8096000);               // 100,663,296
    float* featsF = (float*)(ws + 108759296);                            // 2,555,904
    float* featsB = (float*)(ws + 111315200);                            // 2,555,904
    unsigned short* Whp = (unsigned short*)(ws + 113871104);             // 262,144
    int* prefix = (int*)(ws + 114133248);                                // 257*4 = 1,028

    pack_kernel<<<NG + 1024 + V_, KP, 0, stream>>>(W_ih_f, W_ih_b, W_hh_f, W_hh_b,
                                                   embedding, seq_len, Wp, Whp, Ep, prefix, out);
    gemm_kernel<<<(int)(M / 128) * 8, 256, 0, stream>>>(Ep, sentence, Wp, b_f, b_b, prefix, gx);
    lstm_kernel<<<128, 576, 0, stream>>>(gx, Whp, seq_len, prefix, W_fc, featsF, featsB);
    crf_kernel<<<B_, 64, 0, stream>>>(featsF, featsB, b_fc, trans, tags, seq_len, out);
}